// Round 3
// baseline (429.460 us; speedup 1.0000x reference)
//
#include <hip/hip_runtime.h>
#include <hip/hip_fp16.h>

#define BSZ 4
#define CCH 8
#define NN  8192
#define KK  16
#define DD  64
#define HHD 4
#define FFD 256
#define NT  (BSZ*NN)   // 32768 tokens

// ---------------- workspace layout (in floats) ----------------
#define WS_X0   0
#define WS_XN   (WS_X0 + NT*CCH)          // 262144
#define WS_IDX  (WS_XN + NT*CCH)          // int region, NT*KK ints
#define WS_M    (WS_IDX + NT*KK)          // 256 floats
#define WS_EVO  (WS_M + 256)              // 2048 floats
#define WS_H1   (WS_EVO + 2048)           // NT*64 floats
#define WS_XNH  (WS_H1 + NT*DD)           // NT*8 halves = NT*4 floats

typedef _Float16 h2t __attribute__((ext_vector_type(2)));

__device__ __forceinline__ float fdot2_(h2t a, h2t b, float c) {
#if __has_builtin(__builtin_amdgcn_fdot2)
  return __builtin_amdgcn_fdot2(a, b, c, false);
#else
  return fmaf((float)a[1], (float)b[1], fmaf((float)a[0], (float)b[0], c));
#endif
}

__device__ __forceinline__ float dotcol(const uint4 w, const h2t* qh) {
  float v = fdot2_(__builtin_bit_cast(h2t, w.x), qh[0], 0.f);
  v = fdot2_(__builtin_bit_cast(h2t, w.y), qh[1], v);
  v = fdot2_(__builtin_bit_cast(h2t, w.z), qh[2], v);
  v = fdot2_(__builtin_bit_cast(h2t, w.w), qh[3], v);
  return v;
}

// ---------------- weight fusion (tiny, 1 block) ----------------
__global__ __launch_bounds__(256) void k_fusew(const float* __restrict__ Wemb,
                                               const float* __restrict__ Wqkv,
                                               const float* __restrict__ Wo,
                                               float* __restrict__ Mout,
                                               float* __restrict__ Wevo) {
  __shared__ float eq[512], ek[512], ev[512];
  int tid = threadIdx.x;
  for (int i = tid; i < 1536; i += 256) {
    int w = i >> 9;           // 0=q,1=k,2=v
    int r = i & 511;          // c*64+d
    int c = r >> 6, d = r & 63;
    float s = 0.f;
    for (int e = 0; e < 64; ++e) s = fmaf(Wemb[c*64+e], Wqkv[w*4096 + e*64 + d], s);
    float* dst = (w == 0) ? eq : ((w == 1) ? ek : ev);
    dst[r] = s;
  }
  __syncthreads();
  for (int i = tid; i < 256; i += 256) {
    int h = i >> 6, cp = (i >> 3) & 7, c = i & 7;
    float s = 0.f;
    for (int dd = 0; dd < 16; ++dd) s = fmaf(eq[cp*64 + h*16 + dd], ek[c*64 + h*16 + dd], s);
    Mout[i] = s;
  }
  for (int i = tid; i < 2048; i += 256) {
    int hc = i >> 6, dp = i & 63;
    int h = hc >> 3, c = hc & 7;
    float s = 0.f;
    for (int dd = 0; dd < 16; ++dd) s = fmaf(ev[c*64 + h*16 + dd], Wo[(h*16 + dd)*64 + dp], s);
    Wevo[i] = s;
  }
}

// ---------------- prep: x0, xn, xnh (f16), tgt_out ----------------
__global__ __launch_bounds__(256) void k_prep(const float* __restrict__ xc,
                                              float* __restrict__ x0,
                                              float* __restrict__ xn,
                                              _Float16* __restrict__ xnh,
                                              float* __restrict__ outT) {
  int g = blockIdx.x * 256 + threadIdx.x;       // 0..32767
  int b = g >> 13, n = g & (NN - 1);
  float v[8];
  float ss = 0.f;
#pragma unroll
  for (int c = 0; c < 8; ++c) {
    float t = xc[((size_t)(b*8 + c) * 2) * NN + n];   // x_c[b][c][0][n]
    v[c] = t; ss = fmaf(t, t, ss);
  }
  float inv = 1.f / (sqrtf(ss) + 1e-12f);
  float vn[8];
#pragma unroll
  for (int c = 0; c < 8; ++c) {
    vn[c] = v[c] * inv;
    x0[(size_t)g*8 + c] = v[c];
    xn[(size_t)g*8 + c] = vn[c];
    outT[(size_t)b*8*NN + (size_t)c*NN + n] = v[c];   // tgt_out
  }
  uint4 wh;
  wh.x = __builtin_bit_cast(unsigned, (h2t){(_Float16)vn[0], (_Float16)vn[1]});
  wh.y = __builtin_bit_cast(unsigned, (h2t){(_Float16)vn[2], (_Float16)vn[3]});
  wh.z = __builtin_bit_cast(unsigned, (h2t){(_Float16)vn[4], (_Float16)vn[5]});
  wh.w = __builtin_bit_cast(unsigned, (h2t){(_Float16)vn[6], (_Float16)vn[7]});
  *(uint4*)(xnh + (size_t)g*8) = wh;
}

// ---------------- top-16: sampled threshold + f16-dot filter + exact rank ----------------
#define TPK_R   8       // rows per block
#define TPK_NB  512     // sample-histogram bins over [-1, 1]
#define TPK_CAP 320     // candidate capacity per row

__global__ __launch_bounds__(256, 4) void k_topk(const float* __restrict__ xn,
                                                 const _Float16* __restrict__ xnh,
                                                 int* __restrict__ idxo) {
  __shared__ int   hist[TPK_R][TPK_NB];     // 16 KB
  __shared__ float scv[TPK_R][TPK_CAP];     // 10 KB
  __shared__ int   sci[TPK_R][TPK_CAP];     // 10 KB
  __shared__ float sQ[TPK_R][8];            // fp32 q rows (exact recompute)
  __shared__ float sT[TPK_R];
  __shared__ int   scnt[TPK_R];
  const int tid = threadIdx.x;
  const int rowbase = blockIdx.x * TPK_R;   // 0..32767
  const int b = rowbase >> 13;
  const int m0 = rowbase & (NN - 1);
  const float*    xnb = xn  + (size_t)b * NN * 8;
  const _Float16* xhb = xnh + (size_t)b * NN * 8;

  // q rows as f16 pairs in registers
  h2t qh[TPK_R][4];
#pragma unroll
  for (int r = 0; r < TPK_R; ++r) {
    uint4 wq = *(const uint4*)(xhb + (size_t)(m0 + r) * 8);
    qh[r][0] = __builtin_bit_cast(h2t, wq.x);
    qh[r][1] = __builtin_bit_cast(h2t, wq.y);
    qh[r][2] = __builtin_bit_cast(h2t, wq.z);
    qh[r][3] = __builtin_bit_cast(h2t, wq.w);
  }
  if (tid < 64) sQ[tid >> 3][tid & 7] = xnb[(size_t)(m0 + (tid >> 3)) * 8 + (tid & 7)];
  for (int i = tid; i < TPK_R*TPK_NB; i += 256) ((int*)hist)[i] = 0;
  if (tid < TPK_R) scnt[tid] = 0;
  __syncthreads();

  // ---- sample pass: every 4th column (2048 samples) -> per-row histogram ----
#pragma unroll
  for (int it = 0; it < 8; ++it) {
    int j = (it * 256 + tid) * 4;
    uint4 w = *(const uint4*)(xhb + (size_t)j * 8);
#pragma unroll
    for (int r = 0; r < TPK_R; ++r) {
      float v = dotcol(w, qh[r]);
      int bb = (int)(fmaf(v, 256.f, 256.f));
      bb = bb < 0 ? 0 : (bb > (TPK_NB-1) ? (TPK_NB-1) : bb);
      atomicAdd(&hist[r][bb], 1);
    }
  }
  __syncthreads();

  // ---- wave-parallel threshold: bin edge of sample-16th, minus f16-error margin ----
  {
    int r = tid >> 5, ln = tid & 31;
    int base = TPK_NB - 1 - ln * 16;          // my 16-bin chunk (descending)
    int loc = 0;
#pragma unroll
    for (int u = 0; u < 16; ++u) loc += hist[r][base - u];
    int pre = loc;
#pragma unroll
    for (int off = 1; off < 32; off <<= 1) {
      int t2 = __shfl_up(pre, off, 32);
      if (ln >= off) pre += t2;
    }
    int preex = pre - loc;                    // count in bins above my chunk
    if (preex < KK && pre >= KK) {            // crossing chunk (exactly one lane)
      int cum = preex, bb = base - 15;
      for (int u = 0; u < 16; ++u) { cum += hist[r][base - u]; if (cum >= KK) { bb = base - u; break; } }
      // bin lower edge <= sample 16th-largest <= population 16th-largest.
      // 4e-3 margin covers worst-case f16 dot error (<=2^-10 per dot, x2).
      sT[r] = fmaf((float)bb, 1.f/256.f, -1.f) - 0.004f;
    }
  }
  __syncthreads();
  float tr_[TPK_R];
#pragma unroll
  for (int r = 0; r < TPK_R; ++r) tr_[r] = sT[r];

  // ---- full pass: 4 fdot2 + 1 cmp per dot; rare append ----
  for (int it = 0; it < 32; ++it) {
    int j = it * 256 + tid;
    uint4 w = *(const uint4*)(xhb + (size_t)j * 8);
#pragma unroll
    for (int r = 0; r < TPK_R; ++r) {
      float v = dotcol(w, qh[r]);
      if (v >= tr_[r]) {
        int p = atomicAdd(&scnt[r], 1);
        if (p < TPK_CAP) sci[r][p] = j;
      }
    }
  }
  __syncthreads();

  // ---- exact fp32 recompute of candidates (same fmaf chain as numpy-matching r2) ----
#pragma unroll 1
  for (int r = 0; r < TPK_R; ++r) {
    int n = scnt[r]; if (n > TPK_CAP) n = TPK_CAP;
    for (int s = tid; s < n; s += 256) {
      int j = sci[r][s];
      const float4* xp = (const float4*)(xnb + (size_t)j * 8);
      float4 a = xp[0], c = xp[1];
      float v = a.x * sQ[r][0];
      v = fmaf(a.y, sQ[r][1], v); v = fmaf(a.z, sQ[r][2], v); v = fmaf(a.w, sQ[r][3], v);
      v = fmaf(c.x, sQ[r][4], v); v = fmaf(c.y, sQ[r][5], v);
      v = fmaf(c.z, sQ[r][6], v); v = fmaf(c.w, sQ[r][7], v);
      scv[r][s] = v;
    }
  }
  __syncthreads();

  // ---- exact rank-select among candidates: rank = #better by (v desc, idx asc) ----
  {
    int r = tid >> 5, l32 = tid & 31;
    int n = scnt[r]; if (n > TPK_CAP) n = TPK_CAP;
    for (int s = l32; s < n; s += 32) {
      float v = scv[r][s]; int id = sci[r][s];
      int rank = 0;
      for (int t2 = 0; t2 < n; ++t2) {
        float vo = scv[r][t2]; int io = sci[r][t2];
        rank += (vo > v || (vo == v && io < id)) ? 1 : 0;
      }
      if (rank < KK) idxo[(size_t)(rowbase + r)*KK + rank] = id;
    }
  }
}

// ---------------- attention + W_o + LN1 -> h1 ----------------
__global__ __launch_bounds__(256) void k_attn(const float* __restrict__ x0,
                                              const int* __restrict__ idx,
                                              const float* __restrict__ Wemb,
                                              const float* __restrict__ Mw,
                                              const float* __restrict__ Wevo,
                                              float* __restrict__ h1o) {
  __shared__ float sM[256], sE[512], sV[2048];
  int tid = threadIdx.x;
  for (int i = tid; i < 256;  i += 256) sM[i] = Mw[i];
  for (int i = tid; i < 512;  i += 256) sE[i] = Wemb[i];
  for (int i = tid; i < 2048; i += 256) sV[i] = Wevo[i];
  __syncthreads();
  int l = tid & 63;
  int h = l & 3, kk2 = l >> 2;                  // 4 heads x 16 neighbors
  int wid = blockIdx.x * 4 + (tid >> 6);
  for (int it = 0; it < 4; ++it) {
    int g = wid * 4 + it;
    int b = g >> 13;
    const float4* xq = (const float4*)(x0 + (size_t)g * 8);
    float4 a0 = xq[0], a1 = xq[1];
    float x0q[8] = {a0.x, a0.y, a0.z, a0.w, a1.x, a1.y, a1.z, a1.w};
    int nk = idx[(size_t)g*KK + kk2];
    const float4* xs = (const float4*)(x0 + ((size_t)(b*NN) + nk) * 8);
    float4 s0 = xs[0], s1v = xs[1];
    float sx[8] = {s0.x, s0.y, s0.z, s0.w, s1v.x, s1v.y, s1v.z, s1v.w};
    float qe[8];
#pragma unroll
    for (int c = 0; c < 8; ++c) {
      float s = 0.f;
#pragma unroll
      for (int c2 = 0; c2 < 8; ++c2) s = fmaf(x0q[c2], sM[h*64 + c2*8 + c], s);
      qe[c] = s;
    }
    float att = 0.f;
#pragma unroll
    for (int c = 0; c < 8; ++c) att = fmaf(sx[c], qe[c], att);
    att *= 0.25f;                               // 1/sqrt(DH)
    float mx = att;
#pragma unroll
    for (int off = 4; off <= 32; off <<= 1) mx = fmaxf(mx, __shfl_xor(mx, off));
    float e = __expf(att - mx);
    float sum = e;
#pragma unroll
    for (int off = 4; off <= 32; off <<= 1) sum += __shfl_xor(sum, off);
    float p = e / sum;
    float ps[8];
#pragma unroll
    for (int c = 0; c < 8; ++c) ps[c] = p * sx[c];
#pragma unroll
    for (int off = 4; off <= 32; off <<= 1) {
#pragma unroll
      for (int c = 0; c < 8; ++c) ps[c] += __shfl_xor(ps[c], off);
    }
    float r1 = 0.f;
#pragma unroll
    for (int c = 0; c < 8; ++c) {
      float pc = ps[c];
#pragma unroll
      for (int hh = 0; hh < 4; ++hh) {
        float v = __shfl(pc, hh);               // lane hh holds ps[hh][c]
        r1 = fmaf(v, sV[(hh*8 + c)*64 + l], r1);
      }
    }
#pragma unroll
    for (int c = 0; c < 8; ++c) r1 = fmaf(x0q[c], sE[c*64 + l], r1);
    float s1 = r1, s2 = r1 * r1;
#pragma unroll
    for (int off = 1; off <= 32; off <<= 1) { s1 += __shfl_xor(s1, off); s2 += __shfl_xor(s2, off); }
    float m = s1 * (1.f/64.f), var = s2 * (1.f/64.f) - m*m;
    float h1v = (r1 - m) * rsqrtf(var + 1e-5f);
    h1o[(size_t)g*DD + l] = h1v;
  }
}

// ---------------- FF (relu MLP) + LN2 + W_out -> sq_c ----------------
__global__ __launch_bounds__(256) void k_ff(const float* __restrict__ h1,
                                            const float* __restrict__ W1,
                                            const float* __restrict__ W2,
                                            const float* __restrict__ Wout,
                                            float* __restrict__ outp) {
  __shared__ float  h1t[16*64];       // 4 KB
  __shared__ __half uh[16*260];       // 8.1 KB (row pad 260 halves)
  __shared__ __half w2h[256*66];      // 33 KB  (row pad 66 halves)
  __shared__ float  swout[512];       // 2 KB
  __shared__ float  red[16*16*2];     // 2 KB
  __shared__ float  red2[16*16*8];    // 8 KB
  int tid = threadIdx.x;
  int g0 = blockIdx.x * 16;
  for (int i = tid; i < 1024; i += 256) h1t[i] = h1[(size_t)g0*DD + i];
  {
    int f = tid;                       // stage W2 as fp16
#pragma unroll
    for (int i = 0; i < 64; ++i) w2h[f*66 + i] = __float2half(W2[f*64 + i]);
  }
  for (int i = tid; i < 512; i += 256) swout[i] = Wout[i];
  __syncthreads();
  // phase 1: thread <-> f, W1 column in regs
  {
    float w1[64];
#pragma unroll
    for (int d2 = 0; d2 < 64; ++d2) w1[d2] = W1[d2*256 + tid];
    for (int t = 0; t < 16; ++t) {
      float acc = 0.f;
#pragma unroll
      for (int d4 = 0; d4 < 16; ++d4) {
        float4 hv = *(const float4*)&h1t[t*64 + d4*4];
        acc = fmaf(hv.x, w1[d4*4+0], acc);
        acc = fmaf(hv.y, w1[d4*4+1], acc);
        acc = fmaf(hv.z, w1[d4*4+2], acc);
        acc = fmaf(hv.w, w1[d4*4+3], acc);
      }
      uh[t*260 + tid] = __float2half(fmaxf(acc, 0.f));
    }
  }
  __syncthreads();
  // phase 2: thread <-> (t, d-quad)
  int t = tid >> 4, dq = tid & 15, d0 = dq * 4;
  float acc[4];
#pragma unroll
  for (int j = 0; j < 4; ++j) acc[j] = h1t[t*64 + d0 + j];   // residual h1
#pragma unroll 4
  for (int f = 0; f < 256; ++f) {
    float uf = __half2float(uh[t*260 + f]);
#pragma unroll
    for (int j = 0; j < 4; ++j)
      acc[j] = fmaf(uf, __half2float(w2h[f*66 + d0 + j]), acc[j]);
  }
  float s1 = acc[0] + acc[1] + acc[2] + acc[3];
  float s2 = acc[0]*acc[0] + acc[1]*acc[1] + acc[2]*acc[2] + acc[3]*acc[3];
  red[(t*16 + dq)*2 + 0] = s1; red[(t*16 + dq)*2 + 1] = s2;
  __syncthreads();
  float S1 = 0.f, S2 = 0.f;
#pragma unroll
  for (int i = 0; i < 16; ++i) { S1 += red[(t*16 + i)*2]; S2 += red[(t*16 + i)*2 + 1]; }
  float m = S1 * (1.f/64.f), var = S2 * (1.f/64.f) - m*m;
  float rs = rsqrtf(var + 1e-5f);
  float oc[8] = {0,0,0,0,0,0,0,0};
#pragma unroll
  for (int j = 0; j < 4; ++j) {
    float h2 = (acc[j] - m) * rs;
#pragma unroll
    for (int c = 0; c < 8; ++c) oc[c] = fmaf(h2, swout[(d0 + j)*8 + c], oc[c]);
  }
#pragma unroll
  for (int c = 0; c < 8; ++c) red2[(t*16 + dq)*8 + c] = oc[c];
  __syncthreads();
  if (dq < 8) {
    float s = 0.f;
#pragma unroll
    for (int grp = 0; grp < 16; ++grp) s += red2[(t*16 + grp)*8 + dq];
    outp[(size_t)(g0 + t)*8 + dq] = s;
  }
}

// ---------------- launch ----------------
extern "C" void kernel_launch(void* const* d_in, const int* in_sizes, int n_in,
                              void* d_out, int out_size, void* d_ws, size_t ws_size,
                              hipStream_t stream) {
  const float* xc   = (const float*)d_in[0];
  const float* Wemb = (const float*)d_in[1];
  const float* Wqkv = (const float*)d_in[2];
  const float* Wo   = (const float*)d_in[3];
  const float* W1   = (const float*)d_in[4];
  const float* W2   = (const float*)d_in[5];
  const float* Wout = (const float*)d_in[6];
  float* out = (float*)d_out;
  float* fw  = (float*)d_ws;
  float* x0  = fw + WS_X0;
  float* xn  = fw + WS_XN;
  int*   idx = (int*)(fw + WS_IDX);
  float* Mw  = fw + WS_M;
  float* Wevo= fw + WS_EVO;
  float* h1  = fw + WS_H1;
  _Float16* xnh = (_Float16*)(fw + WS_XNH);

  hipLaunchKernelGGL(k_fusew, dim3(1),          dim3(256), 0, stream, Wemb, Wqkv, Wo, Mw, Wevo);
  hipLaunchKernelGGL(k_prep,  dim3(NT/256),     dim3(256), 0, stream, xc, x0, xn, xnh, out + (size_t)NT*CCH);
  hipLaunchKernelGGL(k_topk,  dim3(NT/TPK_R),   dim3(256), 0, stream, xn, xnh, idx);
  hipLaunchKernelGGL(k_attn,  dim3(2048),       dim3(256), 0, stream, x0, idx, Wemb, Mw, Wevo, h1);
  hipLaunchKernelGGL(k_ff,    dim3(2048),       dim3(256), 0, stream, h1, W1, W2, Wout, out);
}

// Round 4
// 406.103 us; speedup vs baseline: 1.0575x; 1.0575x over previous
//
#include <hip/hip_runtime.h>
#include <hip/hip_fp16.h>

#define BSZ 4
#define CCH 8
#define NN  8192
#define KK  16
#define DD  64
#define HHD 4
#define FFD 256
#define NT  (BSZ*NN)   // 32768 tokens

// ---------------- workspace layout (in floats) ----------------
#define WS_X0   0
#define WS_XN   (WS_X0 + NT*CCH)          // 262144
#define WS_IDX  (WS_XN + NT*CCH)          // int region, NT*KK ints
#define WS_M    (WS_IDX + NT*KK)          // 256 floats
#define WS_EVO  (WS_M + 256)              // 2048 floats
#define WS_H1   (WS_EVO + 2048)           // NT*64 floats
#define WS_XNH  (WS_H1 + NT*DD)           // NT*8 halves = NT*4 floats

typedef _Float16 h2t __attribute__((ext_vector_type(2)));

__device__ __forceinline__ void cvt8(float* wf, uint4 w) {
  h2t a = __builtin_bit_cast(h2t, w.x);
  h2t bb = __builtin_bit_cast(h2t, w.y);
  h2t c = __builtin_bit_cast(h2t, w.z);
  h2t d = __builtin_bit_cast(h2t, w.w);
  wf[0]=(float)a[0]; wf[1]=(float)a[1];
  wf[2]=(float)bb[0]; wf[3]=(float)bb[1];
  wf[4]=(float)c[0]; wf[5]=(float)c[1];
  wf[6]=(float)d[0]; wf[7]=(float)d[1];
}

// ---------------- weight fusion (tiny, 1 block) ----------------
__global__ __launch_bounds__(256) void k_fusew(const float* __restrict__ Wemb,
                                               const float* __restrict__ Wqkv,
                                               const float* __restrict__ Wo,
                                               float* __restrict__ Mout,
                                               float* __restrict__ Wevo) {
  __shared__ float eq[512], ek[512], ev[512];
  int tid = threadIdx.x;
  for (int i = tid; i < 1536; i += 256) {
    int w = i >> 9;           // 0=q,1=k,2=v
    int r = i & 511;          // c*64+d
    int c = r >> 6, d = r & 63;
    float s = 0.f;
    for (int e = 0; e < 64; ++e) s = fmaf(Wemb[c*64+e], Wqkv[w*4096 + e*64 + d], s);
    float* dst = (w == 0) ? eq : ((w == 1) ? ek : ev);
    dst[r] = s;
  }
  __syncthreads();
  for (int i = tid; i < 256; i += 256) {
    int h = i >> 6, cp = (i >> 3) & 7, c = i & 7;
    float s = 0.f;
    for (int dd = 0; dd < 16; ++dd) s = fmaf(eq[cp*64 + h*16 + dd], ek[c*64 + h*16 + dd], s);
    Mout[i] = s;
  }
  for (int i = tid; i < 2048; i += 256) {
    int hc = i >> 6, dp = i & 63;
    int h = hc >> 3, c = hc & 7;
    float s = 0.f;
    for (int dd = 0; dd < 16; ++dd) s = fmaf(ev[c*64 + h*16 + dd], Wo[(h*16 + dd)*64 + dp], s);
    Wevo[i] = s;
  }
}

// ---------------- prep: x0, xn, xnh (f16), tgt_out ----------------
__global__ __launch_bounds__(256) void k_prep(const float* __restrict__ xc,
                                              float* __restrict__ x0,
                                              float* __restrict__ xn,
                                              _Float16* __restrict__ xnh,
                                              float* __restrict__ outT) {
  int g = blockIdx.x * 256 + threadIdx.x;       // 0..32767
  int b = g >> 13, n = g & (NN - 1);
  float v[8];
  float ss = 0.f;
#pragma unroll
  for (int c = 0; c < 8; ++c) {
    float t = xc[((size_t)(b*8 + c) * 2) * NN + n];   // x_c[b][c][0][n]
    v[c] = t; ss = fmaf(t, t, ss);
  }
  float inv = 1.f / (sqrtf(ss) + 1e-12f);
  float vn[8];
#pragma unroll
  for (int c = 0; c < 8; ++c) {
    vn[c] = v[c] * inv;
    x0[(size_t)g*8 + c] = v[c];
    xn[(size_t)g*8 + c] = vn[c];
    outT[(size_t)b*8*NN + (size_t)c*NN + n] = v[c];   // tgt_out
  }
  uint4 wh;
  wh.x = __builtin_bit_cast(unsigned, (h2t){(_Float16)vn[0], (_Float16)vn[1]});
  wh.y = __builtin_bit_cast(unsigned, (h2t){(_Float16)vn[2], (_Float16)vn[3]});
  wh.z = __builtin_bit_cast(unsigned, (h2t){(_Float16)vn[4], (_Float16)vn[5]});
  wh.w = __builtin_bit_cast(unsigned, (h2t){(_Float16)vn[6], (_Float16)vn[7]});
  *(uint4*)(xnh + (size_t)g*8) = wh;
}

// ---------------- top-16: sampled threshold + branch-free filter + exact rank ----------------
#define TPK_R   8       // rows per block
#define TPK_NB  256     // sample-histogram bins over [-1, 1]
#define TPK_CAP 320     // candidate capacity per row

__global__ __launch_bounds__(256, 4) void k_topk(const float* __restrict__ xn,
                                                 const _Float16* __restrict__ xnh,
                                                 int* __restrict__ idxo) {
  __shared__ int   hist[TPK_R][TPK_NB];     // 8 KB
  __shared__ float scv[TPK_R][TPK_CAP];     // 10 KB
  __shared__ int   sci[TPK_R][TPK_CAP];     // 10 KB
  __shared__ float sQ[TPK_R][8];            // fp32 q rows (exact recompute)
  __shared__ float sT[TPK_R];
  __shared__ int   scnt[TPK_R];
  const int tid = threadIdx.x;
  const int rowbase = blockIdx.x * TPK_R;   // 0..32767
  const int b = rowbase >> 13;
  const int m0 = rowbase & (NN - 1);
  const float*    xnb = xn  + (size_t)b * NN * 8;
  const _Float16* xhb = xnh + (size_t)b * NN * 8;

  // fp32 q rows in registers (64 VGPR)
  float qf[TPK_R][8];
#pragma unroll
  for (int r = 0; r < TPK_R; ++r) {
    const float4* qp = (const float4*)(xnb + (size_t)(m0 + r) * 8);
    float4 a = qp[0], c = qp[1];
    qf[r][0]=a.x; qf[r][1]=a.y; qf[r][2]=a.z; qf[r][3]=a.w;
    qf[r][4]=c.x; qf[r][5]=c.y; qf[r][6]=c.z; qf[r][7]=c.w;
  }
  if (tid < 64) sQ[tid >> 3][tid & 7] = xnb[(size_t)(m0 + (tid >> 3)) * 8 + (tid & 7)];
  for (int i = tid; i < TPK_R*TPK_NB; i += 256) ((int*)hist)[i] = 0;
  if (tid < TPK_R) scnt[tid] = 0;
  __syncthreads();

  // ---- sample pass: every 4th column (2048 samples/row) -> per-row histogram ----
#pragma unroll
  for (int it = 0; it < 8; ++it) {
    int j = (it * 256 + tid) * 4;
    uint4 w = *(const uint4*)(xhb + (size_t)j * 8);
    float wf[8]; cvt8(wf, w);
#pragma unroll
    for (int r = 0; r < TPK_R; ++r) {
      float v = wf[0] * qf[r][0];
      v = fmaf(wf[1], qf[r][1], v); v = fmaf(wf[2], qf[r][2], v); v = fmaf(wf[3], qf[r][3], v);
      v = fmaf(wf[4], qf[r][4], v); v = fmaf(wf[5], qf[r][5], v);
      v = fmaf(wf[6], qf[r][6], v); v = fmaf(wf[7], qf[r][7], v);
      int bb = (int)(fmaf(v, 128.f, 128.f));
      bb = bb < 0 ? 0 : (bb > (TPK_NB-1) ? (TPK_NB-1) : bb);
      atomicAdd(&hist[r][bb], 1);
    }
  }
  __syncthreads();

  // ---- wave-parallel threshold: bin edge of sample-16th, minus f16 margin ----
  {
    int r = tid >> 5, ln = tid & 31;
    int base = TPK_NB - 1 - ln * 8;           // my 8-bin chunk (descending)
    int loc = 0;
#pragma unroll
    for (int u = 0; u < 8; ++u) loc += hist[r][base - u];
    int pre = loc;
#pragma unroll
    for (int off = 1; off < 32; off <<= 1) {
      int t2 = __shfl_up(pre, off, 32);
      if (ln >= off) pre += t2;
    }
    int preex = pre - loc;                    // count in bins above my chunk
    if (preex < KK && pre >= KK) {            // crossing chunk (exactly one lane)
      int cum = preex, bb = base - 7;
      for (int u = 0; u < 8; ++u) { cum += hist[r][base - u]; if (cum >= KK) { bb = base - u; break; } }
      // bin lower edge <= sample 16th <= population 16th (of f16-data dots).
      // 3e-3 margin covers 2x worst-case f16-storage dot error (2*1.4e-3).
      sT[r] = fmaf((float)bb, 1.f/128.f, -1.f) - 0.003f;
    }
  }
  __syncthreads();
  float negt[TPK_R];
#pragma unroll
  for (int r = 0; r < TPK_R; ++r) negt[r] = -sT[r];

  // ---- full pass: branch-free dots (acc init = -thr), single rare guard ----
  for (int it = 0; it < 32; ++it) {
    int j = it * 256 + tid;
    uint4 w = *(const uint4*)(xhb + (size_t)j * 8);
    float wf[8]; cvt8(wf, w);
    float vr[TPK_R];
#pragma unroll
    for (int r = 0; r < TPK_R; ++r) {
      float v = fmaf(wf[0], qf[r][0], negt[r]);
      v = fmaf(wf[1], qf[r][1], v); v = fmaf(wf[2], qf[r][2], v); v = fmaf(wf[3], qf[r][3], v);
      v = fmaf(wf[4], qf[r][4], v); v = fmaf(wf[5], qf[r][5], v);
      v = fmaf(wf[6], qf[r][6], v); v = fmaf(wf[7], qf[r][7], v);
      vr[r] = v;
    }
    float mx = fmaxf(fmaxf(fmaxf(vr[0], vr[1]), fmaxf(vr[2], vr[3])),
                     fmaxf(fmaxf(vr[4], vr[5]), fmaxf(vr[6], vr[7])));
    if (mx >= 0.f) {                          // ~7% of iterations
#pragma unroll
      for (int r = 0; r < TPK_R; ++r) {
        if (vr[r] >= 0.f) {
          int p = atomicAdd(&scnt[r], 1);
          if (p < TPK_CAP) sci[r][p] = j;
        }
      }
    }
  }
  __syncthreads();

  // ---- exact fp32 recompute of candidates (numpy-matching fmaf chain) ----
#pragma unroll 1
  for (int r = 0; r < TPK_R; ++r) {
    int n = scnt[r]; if (n > TPK_CAP) n = TPK_CAP;
    for (int s = tid; s < n; s += 256) {
      int j = sci[r][s];
      const float4* xp = (const float4*)(xnb + (size_t)j * 8);
      float4 a = xp[0], c = xp[1];
      float v = a.x * sQ[r][0];
      v = fmaf(a.y, sQ[r][1], v); v = fmaf(a.z, sQ[r][2], v); v = fmaf(a.w, sQ[r][3], v);
      v = fmaf(c.x, sQ[r][4], v); v = fmaf(c.y, sQ[r][5], v);
      v = fmaf(c.z, sQ[r][6], v); v = fmaf(c.w, sQ[r][7], v);
      scv[r][s] = v;
    }
  }
  __syncthreads();

  // ---- exact rank-select among candidates: rank = #better by (v desc, idx asc) ----
  {
    int r = tid >> 5, l32 = tid & 31;
    int n = scnt[r]; if (n > TPK_CAP) n = TPK_CAP;
    for (int s = l32; s < n; s += 32) {
      float v = scv[r][s]; int id = sci[r][s];
      int rank = 0;
      for (int t2 = 0; t2 < n; ++t2) {
        float vo = scv[r][t2]; int io = sci[r][t2];
        rank += (vo > v || (vo == v && io < id)) ? 1 : 0;
      }
      if (rank < KK) idxo[(size_t)(rowbase + r)*KK + rank] = id;
    }
  }
}

// ---------------- attention + W_o + LN1 -> h1 ----------------
__global__ __launch_bounds__(256) void k_attn(const float* __restrict__ x0,
                                              const int* __restrict__ idx,
                                              const float* __restrict__ Wemb,
                                              const float* __restrict__ Mw,
                                              const float* __restrict__ Wevo,
                                              float* __restrict__ h1o) {
  __shared__ float sM[256], sE[512], sV[2048];
  int tid = threadIdx.x;
  for (int i = tid; i < 256;  i += 256) sM[i] = Mw[i];
  for (int i = tid; i < 512;  i += 256) sE[i] = Wemb[i];
  for (int i = tid; i < 2048; i += 256) sV[i] = Wevo[i];
  __syncthreads();
  int l = tid & 63;
  int h = l & 3, kk2 = l >> 2;                  // 4 heads x 16 neighbors
  int wid = blockIdx.x * 4 + (tid >> 6);
  for (int it = 0; it < 4; ++it) {
    int g = wid * 4 + it;
    int b = g >> 13;
    const float4* xq = (const float4*)(x0 + (size_t)g * 8);
    float4 a0 = xq[0], a1 = xq[1];
    float x0q[8] = {a0.x, a0.y, a0.z, a0.w, a1.x, a1.y, a1.z, a1.w};
    int nk = idx[(size_t)g*KK + kk2];
    const float4* xs = (const float4*)(x0 + ((size_t)(b*NN) + nk) * 8);
    float4 s0 = xs[0], s1v = xs[1];
    float sx[8] = {s0.x, s0.y, s0.z, s0.w, s1v.x, s1v.y, s1v.z, s1v.w};
    float qe[8];
#pragma unroll
    for (int c = 0; c < 8; ++c) {
      float s = 0.f;
#pragma unroll
      for (int c2 = 0; c2 < 8; ++c2) s = fmaf(x0q[c2], sM[h*64 + c2*8 + c], s);
      qe[c] = s;
    }
    float att = 0.f;
#pragma unroll
    for (int c = 0; c < 8; ++c) att = fmaf(sx[c], qe[c], att);
    att *= 0.25f;                               // 1/sqrt(DH)
    float mx = att;
#pragma unroll
    for (int off = 4; off <= 32; off <<= 1) mx = fmaxf(mx, __shfl_xor(mx, off));
    float e = __expf(att - mx);
    float sum = e;
#pragma unroll
    for (int off = 4; off <= 32; off <<= 1) sum += __shfl_xor(sum, off);
    float p = e / sum;
    float ps[8];
#pragma unroll
    for (int c = 0; c < 8; ++c) ps[c] = p * sx[c];
#pragma unroll
    for (int off = 4; off <= 32; off <<= 1) {
#pragma unroll
      for (int c = 0; c < 8; ++c) ps[c] += __shfl_xor(ps[c], off);
    }
    float r1 = 0.f;
#pragma unroll
    for (int c = 0; c < 8; ++c) {
      float pc = ps[c];
#pragma unroll
      for (int hh = 0; hh < 4; ++hh) {
        float v = __shfl(pc, hh);               // lane hh holds ps[hh][c]
        r1 = fmaf(v, sV[(hh*8 + c)*64 + l], r1);
      }
    }
#pragma unroll
    for (int c = 0; c < 8; ++c) r1 = fmaf(x0q[c], sE[c*64 + l], r1);
    float s1 = r1, s2 = r1 * r1;
#pragma unroll
    for (int off = 1; off <= 32; off <<= 1) { s1 += __shfl_xor(s1, off); s2 += __shfl_xor(s2, off); }
    float m = s1 * (1.f/64.f), var = s2 * (1.f/64.f) - m*m;
    float h1v = (r1 - m) * rsqrtf(var + 1e-5f);
    h1o[(size_t)g*DD + l] = h1v;
  }
}

// ---------------- FF (relu MLP) + LN2 + W_out -> sq_c ----------------
__global__ __launch_bounds__(256) void k_ff(const float* __restrict__ h1,
                                            const float* __restrict__ W1,
                                            const float* __restrict__ W2,
                                            const float* __restrict__ Wout,
                                            float* __restrict__ outp) {
  __shared__ float  h1t[16*64];       // 4 KB
  __shared__ __half uh[16*260];       // 8.1 KB (row pad 260 halves)
  __shared__ __half w2h[256*66];      // 33 KB  (row pad 66 halves)
  __shared__ float  swout[512];       // 2 KB
  __shared__ float  red[16*16*2];     // 2 KB
  __shared__ float  red2[16*16*8];    // 8 KB
  int tid = threadIdx.x;
  int g0 = blockIdx.x * 16;
  for (int i = tid; i < 1024; i += 256) h1t[i] = h1[(size_t)g0*DD + i];
  {
    int f = tid;                       // stage W2 as fp16
#pragma unroll
    for (int i = 0; i < 64; ++i) w2h[f*66 + i] = __float2half(W2[f*64 + i]);
  }
  for (int i = tid; i < 512; i += 256) swout[i] = Wout[i];
  __syncthreads();
  // phase 1: thread <-> f, W1 column in regs
  {
    float w1[64];
#pragma unroll
    for (int d2 = 0; d2 < 64; ++d2) w1[d2] = W1[d2*256 + tid];
    for (int t = 0; t < 16; ++t) {
      float acc = 0.f;
#pragma unroll
      for (int d4 = 0; d4 < 16; ++d4) {
        float4 hv = *(const float4*)&h1t[t*64 + d4*4];
        acc = fmaf(hv.x, w1[d4*4+0], acc);
        acc = fmaf(hv.y, w1[d4*4+1], acc);
        acc = fmaf(hv.z, w1[d4*4+2], acc);
        acc = fmaf(hv.w, w1[d4*4+3], acc);
      }
      uh[t*260 + tid] = __float2half(fmaxf(acc, 0.f));
    }
  }
  __syncthreads();
  // phase 2: thread <-> (t, d-quad)
  int t = tid >> 4, dq = tid & 15, d0 = dq * 4;
  float acc[4];
#pragma unroll
  for (int j = 0; j < 4; ++j) acc[j] = h1t[t*64 + d0 + j];   // residual h1
#pragma unroll 4
  for (int f = 0; f < 256; ++f) {
    float uf = __half2float(uh[t*260 + f]);
#pragma unroll
    for (int j = 0; j < 4; ++j)
      acc[j] = fmaf(uf, __half2float(w2h[f*66 + d0 + j]), acc[j]);
  }
  float s1 = acc[0] + acc[1] + acc[2] + acc[3];
  float s2 = acc[0]*acc[0] + acc[1]*acc[1] + acc[2]*acc[2] + acc[3]*acc[3];
  red[(t*16 + dq)*2 + 0] = s1; red[(t*16 + dq)*2 + 1] = s2;
  __syncthreads();
  float S1 = 0.f, S2 = 0.f;
#pragma unroll
  for (int i = 0; i < 16; ++i) { S1 += red[(t*16 + i)*2]; S2 += red[(t*16 + i)*2 + 1]; }
  float m = S1 * (1.f/64.f), var = S2 * (1.f/64.f) - m*m;
  float rs = rsqrtf(var + 1e-5f);
  float oc[8] = {0,0,0,0,0,0,0,0};
#pragma unroll
  for (int j = 0; j < 4; ++j) {
    float h2 = (acc[j] - m) * rs;
#pragma unroll
    for (int c = 0; c < 8; ++c) oc[c] = fmaf(h2, swout[(d0 + j)*8 + c], oc[c]);
  }
#pragma unroll
  for (int c = 0; c < 8; ++c) red2[(t*16 + dq)*8 + c] = oc[c];
  __syncthreads();
  if (dq < 8) {
    float s = 0.f;
#pragma unroll
    for (int grp = 0; grp < 16; ++grp) s += red2[(t*16 + grp)*8 + dq];
    outp[(size_t)(g0 + t)*8 + dq] = s;
  }
}

// ---------------- launch ----------------
extern "C" void kernel_launch(void* const* d_in, const int* in_sizes, int n_in,
                              void* d_out, int out_size, void* d_ws, size_t ws_size,
                              hipStream_t stream) {
  const float* xc   = (const float*)d_in[0];
  const float* Wemb = (const float*)d_in[1];
  const float* Wqkv = (const float*)d_in[2];
  const float* Wo   = (const float*)d_in[3];
  const float* W1   = (const float*)d_in[4];
  const float* W2   = (const float*)d_in[5];
  const float* Wout = (const float*)d_in[6];
  float* out = (float*)d_out;
  float* fw  = (float*)d_ws;
  float* x0  = fw + WS_X0;
  float* xn  = fw + WS_XN;
  int*   idx = (int*)(fw + WS_IDX);
  float* Mw  = fw + WS_M;
  float* Wevo= fw + WS_EVO;
  float* h1  = fw + WS_H1;
  _Float16* xnh = (_Float16*)(fw + WS_XNH);

  hipLaunchKernelGGL(k_fusew, dim3(1),          dim3(256), 0, stream, Wemb, Wqkv, Wo, Mw, Wevo);
  hipLaunchKernelGGL(k_prep,  dim3(NT/256),     dim3(256), 0, stream, xc, x0, xn, xnh, out + (size_t)NT*CCH);
  hipLaunchKernelGGL(k_topk,  dim3(NT/TPK_R),   dim3(256), 0, stream, xn, xnh, idx);
  hipLaunchKernelGGL(k_attn,  dim3(2048),       dim3(256), 0, stream, x0, idx, Wemb, Mw, Wevo, h1);
  hipLaunchKernelGGL(k_ff,    dim3(2048),       dim3(256), 0, stream, h1, W1, W2, Wout, out);
}